// Round 2
// baseline (6605.048 us; speedup 1.0000x reference)
//
#include <hip/hip_runtime.h>
#include <math.h>

#define BB 4
#define CC 64
#define HH 256
#define WW 256
#define WF 129
#define NPIX (WF*HH)                 // 33024
#define NS ((size_t)BB*CC*NPIX)      // 8454144 floats per plane-set
#define ANG0 0.0245436926061702596754894014318f   // 2*pi/256

// ---------------- K1: row rfft (x[b,c,y,:] -> R1[b*C+c][k][y]) ----------------
__global__ __launch_bounds__(192) void k_fft_rows(const float* __restrict__ x,
                                                  float* __restrict__ r1re,
                                                  float* __restrict__ r1im) {
    __shared__ float xs[256], twr[256], twi[256];
    int tid = threadIdx.x;
    int bid = blockIdx.x;
    int y = bid & 255;
    int bc = bid >> 8;
    for (int t = tid; t < 256; t += 192) {
        xs[t] = x[(size_t)bc*HH*WW + (size_t)y*WW + t];
        float ang = (float)t * ANG0;
        twr[t] = cosf(ang);
        twi[t] = -sinf(ang);
    }
    __syncthreads();
    if (tid < WF) {
        int k = tid;
        float ar = 0.f, ai = 0.f;
        #pragma unroll 8
        for (int xx = 0; xx < 256; ++xx) {
            int idx = (k*xx) & 255;
            float v = xs[xx];
            ar += v*twr[idx];
            ai += v*twi[idx];
        }
        r1re[((size_t)bc*WF + k)*HH + y] = ar;
        r1im[((size_t)bc*WF + k)*HH + y] = ai;
    }
}

// ------------- K2: column fft + amp/pha (line (bc,k) over y, contiguous) -------------
__global__ __launch_bounds__(256) void k_fft_cols(const float* __restrict__ r1re,
                                                  const float* __restrict__ r1im,
                                                  float* __restrict__ amp,
                                                  float* __restrict__ pha) {
    __shared__ float zr[256], zi[256], twr[256], twi[256];
    int tid = threadIdx.x;
    int bid = blockIdx.x;
    int k = bid % WF;
    int bc = bid / WF;
    size_t base = ((size_t)bc*WF + k)*HH;
    zr[tid] = r1re[base + tid];
    zi[tid] = r1im[base + tid];
    float ang = (float)tid * ANG0;
    twr[tid] = cosf(ang);
    twi[tid] = -sinf(ang);
    __syncthreads();
    int m = tid;
    float ar = 0.f, ai = 0.f;
    #pragma unroll 4
    for (int yy = 0; yy < 256; ++yy) {
        int idx = (m*yy) & 255;
        float cr = twr[idx], ci = twi[idx];
        float vr = zr[yy], vi = zi[yy];
        ar += vr*cr - vi*ci;
        ai += vr*ci + vi*cr;
    }
    amp[base + m] = sqrtf(ar*ar + ai*ai);
    pha[base + m] = atan2f(ai, ar);
}

// ------------- K_pack: [b,c,k,m] -> channel-innermost [b,k,m,c] -------------
__global__ __launch_bounds__(256) void k_pack(const float* __restrict__ src,
                                              float* __restrict__ dst) {
    __shared__ float tile[64][65];
    int tid = threadIdx.x;
    int bid = blockIdx.x;
    int it = bid & 3;
    int rest = bid >> 2;
    int k = rest % WF;
    int b = rest / WF;
    int i0 = it*64;
    int ii = tid & 63;
    int cg = tid >> 6;
    for (int rep = 0; rep < 16; ++rep) {
        int c = cg*16 + rep;
        tile[c][ii] = src[(size_t)(b*CC + c)*NPIX + (size_t)k*HH + i0 + ii];
    }
    __syncthreads();
    for (int rep = 0; rep < 16; ++rep) {
        int m = cg*16 + rep;
        dst[((size_t)(b*WF + k)*HH + i0 + m)*CC + ii] = tile[ii][m];
    }
}

// ------------- K_wt: wc[oc][c][3][3] -> wct[pos][c][oc] -------------
__global__ void k_wt(const float* __restrict__ wc, float* __restrict__ wct) {
    int idx = blockIdx.x*256 + threadIdx.x;
    if (idx < 9*64*64) {
        int oc = idx & 63;
        int t = idx >> 6;
        int c = t & 63;
        int pos = t >> 6;
        wct[idx] = wc[((size_t)oc*64 + c)*9 + pos];
    }
}

// ------------- K3: offset conv 3x3 (amp layout [b,c,k,m], out [b,18,k,m]) -------------
__global__ __launch_bounds__(256) void k_off_conv(const float* __restrict__ img,
                                                  const float* __restrict__ wp,
                                                  const float* __restrict__ bp,
                                                  float* __restrict__ off) {
    int tid = threadIdx.x;                // i (m)
    int bid = blockIdx.x;
    int j = bid % WF;
    int t = bid / WF;
    int oc = t % 18;
    int b = t / 18;
    float acc = bp[oc];
    for (int c = 0; c < CC; ++c) {
        const float* ib = img + (size_t)(b*CC + c)*NPIX;
        const float* wb = wp + ((size_t)oc*CC + c)*9;
        #pragma unroll
        for (int dj = 0; dj < 3; ++dj) {
            int jj = j + dj - 1;
            if (jj < 0 || jj >= WF) continue;
            const float* col = ib + (size_t)jj*HH;
            #pragma unroll
            for (int di = 0; di < 3; ++di) {
                int ii = tid + di - 1;
                float v = (ii >= 0 && ii < HH) ? col[ii] : 0.f;
                acc += wb[di*3 + dj] * v;
            }
        }
    }
    off[((size_t)(b*18 + oc)*WF + j)*HH + tid] = acc;
}

// ------------- K4: deformable sampling + stride-3 conv, fused -------------
// imgc: channel-innermost [b,k,m,c]; off: [b,18,k,m]; wct: [pos][c][oc]; out: [b,oc,k,m]
__global__ __launch_bounds__(256) void k_deform(const float* __restrict__ imgc,
                                                const float* __restrict__ off,
                                                const float* __restrict__ wct,
                                                float* __restrict__ out) {
    __shared__ int   cidx[4][144];
    __shared__ float cwgt[4][144];
    __shared__ __align__(16) float S[16*580];
    int tid = threadIdx.x;
    int bid = blockIdx.x;
    int it = bid & 15;
    int rest = bid >> 4;
    int j = rest % WF;
    int b = rest / WF;
    int i0 = it * 16;

    if (tid < 144) {
        int pix = tid / 9;
        int pos = tid % 9;
        int ki = pos / 3, kj = pos % 3;
        int i = i0 + pix;
        int r = 3*i + ki - 1;
        int s = 3*j + kj - 1;
        float g[4] = {0.f,0.f,0.f,0.f};
        int ix[4] = {-1,-1,-1,-1};
        if (r >= 0 && s >= 0) {
            int hq = r/3, nx = r%3;
            int wq = s/3, ny = s%3;
            int n = nx*3 + ny;
            float ox = off[((size_t)(b*18 + n)*WF + wq)*HH + hq];
            float oy = off[((size_t)(b*18 + 9 + n)*WF + wq)*HH + hq];
            float pxf = (float)(hq + nx) + ox;
            float pyf = (float)(wq + ny) + oy;
            float qx = floorf(pxf), qy = floorf(pyf);
            float qltx = fminf(fmaxf(qx, 0.f), 257.f);
            float qlty = fminf(fmaxf(qy, 0.f), 130.f);
            float qrbx = fminf(fmaxf(qx + 1.f, 0.f), 257.f);
            float qrby = fminf(fmaxf(qy + 1.f, 0.f), 130.f);
            float pxc = fminf(fmaxf(pxf, 0.f), 257.f);
            float pyc = fminf(fmaxf(pyf, 0.f), 130.f);
            float glt = (1.f + (qltx - pxc)) * (1.f + (qlty - pyc));
            float grb = (1.f - (qrbx - pxc)) * (1.f - (qrby - pyc));
            float glb = (1.f + (qltx - pxc)) * (1.f - (qrby - pyc));
            float grt = (1.f - (qrbx - pxc)) * (1.f + (qlty - pyc));
            int ax0 = (int)qltx, ax1 = (int)qrbx;
            int ay0 = (int)qlty, ay1 = (int)qrby;
            int cx[4] = {ax0, ax1, ax0, ax1};
            int cy[4] = {ay0, ay1, ay1, ay0};
            g[0]=glt; g[1]=grb; g[2]=glb; g[3]=grt;
            #pragma unroll
            for (int q = 0; q < 4; ++q) {
                int a = cx[q], bq = cy[q];
                ix[q] = (a >= 1 && a <= 256 && bq >= 1 && bq <= 129)
                        ? ((bq-1)*HH + (a-1))*CC : -1;
            }
        }
        #pragma unroll
        for (int q = 0; q < 4; ++q) { cidx[q][tid] = ix[q]; cwgt[q][tid] = g[q]; }
    }
    __syncthreads();

    // phase B: 144 combos x 64 channels, c = lane -> coalesced gathers
    const float* cb = imgc + (size_t)b * (size_t)WF * HH * CC;
    for (int t = tid; t < 144*64; t += 256) {
        int combo = t >> 6;
        int c = t & 63;
        float sum = 0.f;
        #pragma unroll
        for (int q = 0; q < 4; ++q) {
            int ofs = cidx[q][combo];
            float v = (ofs >= 0) ? cb[(size_t)ofs + c] : 0.f;
            sum += cwgt[q][combo] * v;
        }
        int pix = combo / 9, pos = combo % 9;
        S[pix*580 + pos*64 + c] = sum;
    }
    __syncthreads();

    // phase C: per-pixel 576-dot with wct -> 64 oc
    int pix = tid & 15;
    int oc0 = (tid >> 4) * 4;
    const float* Sp = &S[pix*580];
    float ac[4] = {0.f,0.f,0.f,0.f};
    for (int kk = 0; kk < 576; kk += 4) {
        float4 sv = *(const float4*)&Sp[kk];
        #pragma unroll
        for (int q = 0; q < 4; ++q) {
            float4 wv = *(const float4*)&wct[(size_t)(kk+q)*64 + oc0];
            float sc = (q==0)? sv.x : (q==1)? sv.y : (q==2)? sv.z : sv.w;
            ac[0] += sc*wv.x; ac[1] += sc*wv.y; ac[2] += sc*wv.z; ac[3] += sc*wv.w;
        }
    }
    size_t ob = (size_t)b*CC*NPIX + (size_t)j*HH + i0 + pix;
    #pragma unroll
    for (int q = 0; q < 4; ++q)
        out[ob + (size_t)(oc0+q)*NPIX] = ac[q];
}

// ------------- K5: fused 1x1 convs + trig combine -------------
// ampc/phac: channel-innermost [b,k,m,c]. a3/p3: [b,c,k,m], overwritten in place
// with out_c real/imag at the same indices.
__global__ __launch_bounds__(256) void k_combine(const float* __restrict__ ampc,
                                                 const float* __restrict__ phac,
                                                 float* __restrict__ a3,
                                                 float* __restrict__ p3,
                                                 const float* __restrict__ w1a,
                                                 const float* __restrict__ b1a,
                                                 const float* __restrict__ w1p,
                                                 const float* __restrict__ b1p) {
    __shared__ float la[64][65], lp[64][65];
    int tid = threadIdx.x;
    int bid = blockIdx.x;
    int quarter = bid & 3;
    int rest = bid >> 2;
    int j = rest % WF;
    int b = rest / WF;
    int i0 = quarter * 64;
    size_t gbase = ((size_t)(b*WF + j)*HH + i0) * CC;
    for (int rep = 0; rep < 16; ++rep) {
        int t = rep*256 + tid;
        int pix = t >> 6;
        int c = t & 63;
        la[c][pix] = ampc[gbase + t];
        lp[c][pix] = phac[gbase + t];
    }
    __syncthreads();
    int ii = tid & 63;     // pixel
    int wv = tid >> 6;     // oc group (16 ocs each)
    float acc_a[16], acc_p[16];
    #pragma unroll
    for (int q = 0; q < 16; ++q) { acc_a[q] = b1a[wv*16+q]; acc_p[q] = b1p[wv*16+q]; }
    for (int c = 0; c < CC; ++c) {
        float av = la[c][ii], pv = lp[c][ii];
        #pragma unroll
        for (int q = 0; q < 16; ++q) {
            acc_a[q] += w1a[(wv*16+q)*CC + c] * av;
            acc_p[q] += w1p[(wv*16+q)*CC + c] * pv;
        }
    }
    #pragma unroll
    for (int q = 0; q < 16; ++q) {
        int oc = wv*16 + q;
        size_t idx = (size_t)(b*CC + oc)*NPIX + (size_t)j*HH + i0 + ii;
        float a3v = a3[idx];
        float p3v = p3[idx];
        float s1, c1, s3, c3;
        sincosf(acc_p[q], &s1, &c1);
        sincosf(p3v, &s3, &c3);
        float re = acc_a[q]*c3 + a3v*c1 + 3e-8f;
        float im = a3v*s1 + acc_a[q]*s3 + 2e-8f;
        a3[idx] = re;
        p3[idx] = im;
    }
}

// ------------- K6: inverse column fft (over m), write natural [bc,y,k] -------------
__global__ __launch_bounds__(256) void k_ifft_cols(const float* __restrict__ ocre,
                                                   const float* __restrict__ ocim,
                                                   float* __restrict__ r2re,
                                                   float* __restrict__ r2im) {
    __shared__ float zr[256], zi[256], twr[256], twi[256];
    int tid = threadIdx.x;
    int bid = blockIdx.x;
    int k = bid % WF;
    int bc = bid / WF;
    size_t base = ((size_t)bc*WF + k)*HH;
    zr[tid] = ocre[base + tid];
    zi[tid] = ocim[base + tid];
    float ang = (float)tid * ANG0;
    twr[tid] = cosf(ang);
    twi[tid] = sinf(ang);
    __syncthreads();
    int y = tid;
    float ar = 0.f, ai = 0.f;
    #pragma unroll 4
    for (int m = 0; m < 256; ++m) {
        int idx = (y*m) & 255;
        float cr = twr[idx], ci = twi[idx];
        float vr = zr[m], vi = zi[m];
        ar += vr*cr - vi*ci;
        ai += vr*ci + vi*cr;
    }
    size_t ob = ((size_t)bc*HH + y)*WF + k;
    r2re[ob] = ar * (1.0f/256.0f);
    r2im[ob] = ai * (1.0f/256.0f);
}

// ------------- K7: hermitian row irfft + abs -> xr[b,c,y,x] -------------
__global__ __launch_bounds__(256) void k_irfft_rows(const float* __restrict__ r2re,
                                                    const float* __restrict__ r2im,
                                                    float* __restrict__ xr) {
    __shared__ float Xr[WF], Xi[WF], twc[256], tws[256];
    int tid = threadIdx.x;
    int bid = blockIdx.x;
    int y = bid & 255;
    int bc = bid >> 8;
    size_t base = ((size_t)bc*HH + y)*WF;
    if (tid < WF) {
        Xr[tid] = r2re[base + tid];
        Xi[tid] = r2im[base + tid];
    }
    float ang = (float)tid * ANG0;
    twc[tid] = cosf(ang);
    tws[tid] = sinf(ang);
    __syncthreads();
    int xx = tid;
    float sum = Xr[0] + ((xx & 1) ? -Xr[128] : Xr[128]);
    #pragma unroll 8
    for (int k = 1; k < 128; ++k) {
        int idx = (k*xx) & 255;
        sum += 2.f * (Xr[k]*twc[idx] - Xi[k]*tws[idx]);
    }
    xr[((size_t)bc*HH + y)*WW + xx] = fabsf(sum * (1.0f/256.0f));
}

// ------------- K8: final 5x5 conv, all 64 oc per block -------------
__global__ __launch_bounds__(256) void k_conv5(const float* __restrict__ xr,
                                               const float* __restrict__ w0,
                                               const float* __restrict__ b0,
                                               float* __restrict__ out) {
    __shared__ float rl[5][260];
    int tid = threadIdx.x;                // x
    int bid = blockIdx.x;
    int y = bid & 255;
    int b = bid >> 8;
    float acc[64];
    #pragma unroll
    for (int o = 0; o < 64; ++o) acc[o] = b0[o];
    for (int c = 0; c < CC; ++c) {
        __syncthreads();
        const float* xb = xr + (size_t)(b*CC + c)*HH*WW;
        for (int t = tid; t < 5*260; t += 256) {
            int dy = t / 260;
            int u = t % 260;
            int yy = y + dy - 2;
            int xs = u - 2;
            rl[dy][u] = (yy >= 0 && yy < HH && xs >= 0 && xs < WW)
                        ? xb[(size_t)yy*WW + xs] : 0.f;
        }
        __syncthreads();
        float r[25];
        #pragma unroll
        for (int dy = 0; dy < 5; ++dy)
            #pragma unroll
            for (int dx = 0; dx < 5; ++dx)
                r[dy*5+dx] = rl[dy][tid + dx];
        const float* wb = w0 + (size_t)c*25;
        #pragma unroll
        for (int o = 0; o < 64; ++o) {
            const float* wo = wb + (size_t)o*CC*25;
            float a = acc[o];
            #pragma unroll
            for (int t2 = 0; t2 < 25; ++t2) a += wo[t2] * r[t2];
            acc[o] = a;
        }
    }
    size_t ob = ((size_t)(b*CC)*HH + y)*WW + tid;
    #pragma unroll
    for (int o = 0; o < 64; ++o) out[ob + (size_t)o*HH*WW] = acc[o];
}

extern "C" void kernel_launch(void* const* d_in, const int* in_sizes, int n_in,
                              void* d_out, int out_size, void* d_ws, size_t ws_size,
                              hipStream_t stream) {
    const float* x    = (const float*)d_in[0];
    const float* wp_a = (const float*)d_in[1];
    const float* bp_a = (const float*)d_in[2];
    const float* wc_a = (const float*)d_in[3];
    const float* w1_a = (const float*)d_in[4];
    const float* b1_a = (const float*)d_in[5];
    const float* wp_p = (const float*)d_in[6];
    const float* bp_p = (const float*)d_in[7];
    const float* wc_p = (const float*)d_in[8];
    const float* w1_p = (const float*)d_in[9];
    const float* b1_p = (const float*)d_in[10];
    const float* w0   = (const float*)d_in[11];
    const float* b0   = (const float*)d_in[12];
    float* out = (float*)d_out;
    float* ws  = (float*)d_ws;

    // Workspace map (floats). Peak = 4*NS + off/wct = 38,645,760 floats = 154.6 MB.
    //   R0 (2*NS): r1re/r1im -> ampc/phac -> r2re/r2im
    //   R1 (2*NS): amp/pha  -> A3/P3 -> ocre/ocim (in-place) -> xr
    //   R2: offa/offp + wcta/wctp
    float* R0 = ws;
    float* R1 = ws + 2*NS;
    float* R2 = ws + 4*NS;

    float* r1re = R0;
    float* r1im = R0 + NS;
    float* amp  = R1;
    float* pha  = R1 + NS;
    float* ampc = R0;
    float* phac = R0 + NS;
    size_t offsz = (size_t)BB*18*NPIX;       // 2,377,728
    float* offa = R2;
    float* offp = R2 + offsz;
    float* wcta = R2 + 2*offsz;
    float* wctp = wcta + 9*64*64;
    float* A3   = R1;        // overwrites amp/pha after their last read
    float* P3   = R1 + NS;
    float* r2re = R0;        // overwrites ampc/phac after their last read
    float* r2im = R0 + NS;
    float* xrp  = R1;        // overwrites oc after its last read (needs 16.78M <= 2*NS)

    k_wt<<<144, 256, 0, stream>>>(wc_a, wcta);
    k_wt<<<144, 256, 0, stream>>>(wc_p, wctp);
    k_fft_rows<<<BB*CC*HH, 192, 0, stream>>>(x, r1re, r1im);
    k_fft_cols<<<BB*CC*WF, 256, 0, stream>>>(r1re, r1im, amp, pha);
    k_pack<<<BB*WF*4, 256, 0, stream>>>(amp, ampc);
    k_pack<<<BB*WF*4, 256, 0, stream>>>(pha, phac);
    k_off_conv<<<BB*18*WF, 256, 0, stream>>>(amp, wp_a, bp_a, offa);
    k_off_conv<<<BB*18*WF, 256, 0, stream>>>(pha, wp_p, bp_p, offp);
    k_deform<<<BB*WF*16, 256, 0, stream>>>(ampc, offa, wcta, A3);
    k_deform<<<BB*WF*16, 256, 0, stream>>>(phac, offp, wctp, P3);
    k_combine<<<BB*WF*4, 256, 0, stream>>>(ampc, phac, A3, P3, w1_a, b1_a, w1_p, b1_p);
    k_ifft_cols<<<BB*CC*WF, 256, 0, stream>>>(A3, P3, r2re, r2im);
    k_irfft_rows<<<BB*CC*HH, 256, 0, stream>>>(r2re, r2im, xrp);
    k_conv5<<<BB*HH, 256, 0, stream>>>(xrp, w0, b0, out);
}

// Round 3
// 4315.929 us; speedup vs baseline: 1.5304x; 1.5304x over previous
//
#include <hip/hip_runtime.h>
#include <math.h>

#define BB 4
#define CC 64
#define HH 256
#define WW 256
#define WF 129
#define NPIX (WF*HH)                 // 33024
#define NS ((size_t)BB*CC*NPIX)      // 8454144 floats per plane-set
#define TWOPI 6.283185307179586f

// ---------------- four-step 256-point complex FFT in LDS ----------------
__device__ __forceinline__ float2 cmulf(float2 a, float2 b) {
    return make_float2(a.x*b.x - a.y*b.y, a.x*b.y + a.y*b.x);
}

// xs fully populated + __syncthreads() done by caller. SIGN=-1 fwd, +1 inv.
// Returns X[t] for thread t. Clobbers ys.
template<int SIGN>
__device__ __forceinline__ float2 fft256_lds(const float2* __restrict__ xs,
                                             float2* __restrict__ ys, int t) {
    int k1 = t & 15, n2 = t >> 4;
    // stage A: y[k1][n2] = sum_n1 x[n1*16+n2] * W16^(n1*k1), then * W256^(n2*k1)
    float s1, c1;
    sincosf((float)SIGN * (TWOPI/16.f) * (float)k1, &s1, &c1);
    float2 rb = make_float2(c1, s1);
    float2 w = make_float2(1.f, 0.f);
    float2 acc = make_float2(0.f, 0.f);
    #pragma unroll
    for (int n1 = 0; n1 < 16; ++n1) {
        float2 v = xs[n1*16 + n2];
        acc.x = fmaf(v.x, w.x, fmaf(-v.y, w.y, acc.x));
        acc.y = fmaf(v.x, w.y, fmaf( v.y, w.x, acc.y));
        w = cmulf(w, rb);
    }
    float s2, c2;
    sincosf((float)SIGN * (TWOPI/256.f) * (float)(n2*k1), &s2, &c2);
    ys[t] = cmulf(acc, make_float2(c2, s2));
    __syncthreads();
    // stage B: X[k1+16*k2] = sum_n2 y[k1][n2] * W16^(n2*k2), k2 = t>>4
    float s3, c3;
    sincosf((float)SIGN * (TWOPI/16.f) * (float)n2, &s3, &c3);
    float2 rb2 = make_float2(c3, s3);
    float2 w2 = make_float2(1.f, 0.f);
    float2 acc2 = make_float2(0.f, 0.f);
    #pragma unroll
    for (int m2 = 0; m2 < 16; ++m2) {
        float2 v = ys[m2*16 + k1];
        acc2.x = fmaf(v.x, w2.x, fmaf(-v.y, w2.y, acc2.x));
        acc2.y = fmaf(v.x, w2.y, fmaf( v.y, w2.x, acc2.y));
        w2 = cmulf(w2, rb2);
    }
    return acc2;
}

// ---------------- K1: row rfft (x[b,c,y,:] -> R1[b*C+c][k][y]) ----------------
__global__ __launch_bounds__(256) void k_fft_rows(const float* __restrict__ x,
                                                  float* __restrict__ r1re,
                                                  float* __restrict__ r1im) {
    __shared__ float2 xs[256], ys[256];
    int t = threadIdx.x;
    int bid = blockIdx.x;
    int y = bid & 255;
    int bc = bid >> 8;
    xs[t] = make_float2(x[(size_t)bc*HH*WW + (size_t)y*WW + t], 0.f);
    __syncthreads();
    float2 X = fft256_lds<-1>(xs, ys, t);
    if (t < WF) {
        r1re[((size_t)bc*WF + t)*HH + y] = X.x;
        r1im[((size_t)bc*WF + t)*HH + y] = X.y;
    }
}

// ------------- K2: column fft + amp/pha (line (bc,k) over y, contiguous) -------------
__global__ __launch_bounds__(256) void k_fft_cols(const float* __restrict__ r1re,
                                                  const float* __restrict__ r1im,
                                                  float* __restrict__ amp,
                                                  float* __restrict__ pha) {
    __shared__ float2 xs[256], ys[256];
    int t = threadIdx.x;
    int bid = blockIdx.x;
    int k = bid % WF;
    int bc = bid / WF;
    size_t base = ((size_t)bc*WF + k)*HH;
    xs[t] = make_float2(r1re[base + t], r1im[base + t]);
    __syncthreads();
    float2 X = fft256_lds<-1>(xs, ys, t);
    amp[base + t] = sqrtf(X.x*X.x + X.y*X.y);
    pha[base + t] = atan2f(X.y, X.x);
}

// ------------- K_pack: [b,c,k,m] -> channel-innermost [b,k,m,c] -------------
__global__ __launch_bounds__(256) void k_pack(const float* __restrict__ src,
                                              float* __restrict__ dst) {
    __shared__ float tile[64][65];
    int tid = threadIdx.x;
    int bid = blockIdx.x;
    int it = bid & 3;
    int rest = bid >> 2;
    int k = rest % WF;
    int b = rest / WF;
    int i0 = it*64;
    int ii = tid & 63;
    int cg = tid >> 6;
    for (int rep = 0; rep < 16; ++rep) {
        int c = cg*16 + rep;
        tile[c][ii] = src[(size_t)(b*CC + c)*NPIX + (size_t)k*HH + i0 + ii];
    }
    __syncthreads();
    for (int rep = 0; rep < 16; ++rep) {
        int m = cg*16 + rep;
        dst[((size_t)(b*WF + k)*HH + i0 + m)*CC + ii] = tile[ii][m];
    }
}

// ------------- K_wt: wc[oc][c][3][3] -> wct[pos][c][oc] -------------
__global__ void k_wt(const float* __restrict__ wc, float* __restrict__ wct) {
    int idx = blockIdx.x*256 + threadIdx.x;
    if (idx < 9*64*64) {
        int oc = idx & 63;
        int t = idx >> 6;
        int c = t & 63;
        int pos = t >> 6;
        wct[idx] = wc[((size_t)oc*64 + c)*9 + pos];
    }
}

// ------------- K3: offset conv 3x3 (amp layout [b,c,k,m], out [b,18,k,m]) -------------
__global__ __launch_bounds__(256) void k_off_conv(const float* __restrict__ img,
                                                  const float* __restrict__ wp,
                                                  const float* __restrict__ bp,
                                                  float* __restrict__ off) {
    int tid = threadIdx.x;                // i (m)
    int bid = blockIdx.x;
    int j = bid % WF;
    int t = bid / WF;
    int oc = t % 18;
    int b = t / 18;
    float acc = bp[oc];
    for (int c = 0; c < CC; ++c) {
        const float* ib = img + (size_t)(b*CC + c)*NPIX;
        const float* wb = wp + ((size_t)oc*CC + c)*9;
        #pragma unroll
        for (int dj = 0; dj < 3; ++dj) {
            int jj = j + dj - 1;
            if (jj < 0 || jj >= WF) continue;
            const float* col = ib + (size_t)jj*HH;
            #pragma unroll
            for (int di = 0; di < 3; ++di) {
                int ii = tid + di - 1;
                float v = (ii >= 0 && ii < HH) ? col[ii] : 0.f;
                acc += wb[di*3 + dj] * v;
            }
        }
    }
    off[((size_t)(b*18 + oc)*WF + j)*HH + tid] = acc;
}

// ------------- K4: deformable sampling + stride-3 conv, fused -------------
__global__ __launch_bounds__(256) void k_deform(const float* __restrict__ imgc,
                                                const float* __restrict__ off,
                                                const float* __restrict__ wct,
                                                float* __restrict__ out) {
    __shared__ int   cidx[4][144];
    __shared__ float cwgt[4][144];
    __shared__ __align__(16) float S[16*580];
    int tid = threadIdx.x;
    int bid = blockIdx.x;
    int it = bid & 15;
    int rest = bid >> 4;
    int j = rest % WF;
    int b = rest / WF;
    int i0 = it * 16;

    if (tid < 144) {
        int pix = tid / 9;
        int pos = tid % 9;
        int ki = pos / 3, kj = pos % 3;
        int i = i0 + pix;
        int r = 3*i + ki - 1;
        int s = 3*j + kj - 1;
        float g[4] = {0.f,0.f,0.f,0.f};
        int ix[4] = {-1,-1,-1,-1};
        if (r >= 0 && s >= 0) {
            int hq = r/3, nx = r%3;
            int wq = s/3, ny = s%3;
            int n = nx*3 + ny;
            float ox = off[((size_t)(b*18 + n)*WF + wq)*HH + hq];
            float oy = off[((size_t)(b*18 + 9 + n)*WF + wq)*HH + hq];
            float pxf = (float)(hq + nx) + ox;
            float pyf = (float)(wq + ny) + oy;
            float qx = floorf(pxf), qy = floorf(pyf);
            float qltx = fminf(fmaxf(qx, 0.f), 257.f);
            float qlty = fminf(fmaxf(qy, 0.f), 130.f);
            float qrbx = fminf(fmaxf(qx + 1.f, 0.f), 257.f);
            float qrby = fminf(fmaxf(qy + 1.f, 0.f), 130.f);
            float pxc = fminf(fmaxf(pxf, 0.f), 257.f);
            float pyc = fminf(fmaxf(pyf, 0.f), 130.f);
            float glt = (1.f + (qltx - pxc)) * (1.f + (qlty - pyc));
            float grb = (1.f - (qrbx - pxc)) * (1.f - (qrby - pyc));
            float glb = (1.f + (qltx - pxc)) * (1.f - (qrby - pyc));
            float grt = (1.f - (qrbx - pxc)) * (1.f + (qlty - pyc));
            int ax0 = (int)qltx, ax1 = (int)qrbx;
            int ay0 = (int)qlty, ay1 = (int)qrby;
            int cx[4] = {ax0, ax1, ax0, ax1};
            int cy[4] = {ay0, ay1, ay1, ay0};
            g[0]=glt; g[1]=grb; g[2]=glb; g[3]=grt;
            #pragma unroll
            for (int q = 0; q < 4; ++q) {
                int a = cx[q], bq = cy[q];
                ix[q] = (a >= 1 && a <= 256 && bq >= 1 && bq <= 129)
                        ? ((bq-1)*HH + (a-1))*CC : -1;
            }
        }
        #pragma unroll
        for (int q = 0; q < 4; ++q) { cidx[q][tid] = ix[q]; cwgt[q][tid] = g[q]; }
    }
    __syncthreads();

    const float* cb = imgc + (size_t)b * (size_t)WF * HH * CC;
    for (int t = tid; t < 144*64; t += 256) {
        int combo = t >> 6;
        int c = t & 63;
        float sum = 0.f;
        #pragma unroll
        for (int q = 0; q < 4; ++q) {
            int ofs = cidx[q][combo];
            float v = (ofs >= 0) ? cb[(size_t)ofs + c] : 0.f;
            sum += cwgt[q][combo] * v;
        }
        int pix = combo / 9, pos = combo % 9;
        S[pix*580 + pos*64 + c] = sum;
    }
    __syncthreads();

    int pix = tid & 15;
    int oc0 = (tid >> 4) * 4;
    const float* Sp = &S[pix*580];
    float ac[4] = {0.f,0.f,0.f,0.f};
    for (int kk = 0; kk < 576; kk += 4) {
        float4 sv = *(const float4*)&Sp[kk];
        #pragma unroll
        for (int q = 0; q < 4; ++q) {
            float4 wv = *(const float4*)&wct[(size_t)(kk+q)*64 + oc0];
            float sc = (q==0)? sv.x : (q==1)? sv.y : (q==2)? sv.z : sv.w;
            ac[0] += sc*wv.x; ac[1] += sc*wv.y; ac[2] += sc*wv.z; ac[3] += sc*wv.w;
        }
    }
    size_t ob = (size_t)b*CC*NPIX + (size_t)j*HH + i0 + pix;
    #pragma unroll
    for (int q = 0; q < 4; ++q)
        out[ob + (size_t)(oc0+q)*NPIX] = ac[q];
}

// ------------- K5: fused 1x1 convs + trig combine -------------
__global__ __launch_bounds__(256) void k_combine(const float* __restrict__ ampc,
                                                 const float* __restrict__ phac,
                                                 float* __restrict__ a3,
                                                 float* __restrict__ p3,
                                                 const float* __restrict__ w1a,
                                                 const float* __restrict__ b1a,
                                                 const float* __restrict__ w1p,
                                                 const float* __restrict__ b1p) {
    __shared__ float la[64][65], lp[64][65];
    int tid = threadIdx.x;
    int bid = blockIdx.x;
    int quarter = bid & 3;
    int rest = bid >> 2;
    int j = rest % WF;
    int b = rest / WF;
    int i0 = quarter * 64;
    size_t gbase = ((size_t)(b*WF + j)*HH + i0) * CC;
    for (int rep = 0; rep < 16; ++rep) {
        int t = rep*256 + tid;
        int pix = t >> 6;
        int c = t & 63;
        la[c][pix] = ampc[gbase + t];
        lp[c][pix] = phac[gbase + t];
    }
    __syncthreads();
    int ii = tid & 63;
    int wv = tid >> 6;
    float acc_a[16], acc_p[16];
    #pragma unroll
    for (int q = 0; q < 16; ++q) { acc_a[q] = b1a[wv*16+q]; acc_p[q] = b1p[wv*16+q]; }
    for (int c = 0; c < CC; ++c) {
        float av = la[c][ii], pv = lp[c][ii];
        #pragma unroll
        for (int q = 0; q < 16; ++q) {
            acc_a[q] += w1a[(wv*16+q)*CC + c] * av;
            acc_p[q] += w1p[(wv*16+q)*CC + c] * pv;
        }
    }
    #pragma unroll
    for (int q = 0; q < 16; ++q) {
        int oc = wv*16 + q;
        size_t idx = (size_t)(b*CC + oc)*NPIX + (size_t)j*HH + i0 + ii;
        float a3v = a3[idx];
        float p3v = p3[idx];
        float s1, c1, s3, c3;
        sincosf(acc_p[q], &s1, &c1);
        sincosf(p3v, &s3, &c3);
        float re = acc_a[q]*c3 + a3v*c1 + 3e-8f;
        float im = a3v*s1 + acc_a[q]*s3 + 2e-8f;
        a3[idx] = re;
        p3[idx] = im;
    }
}

// ------------- K6: inverse column fft (over m), write natural [bc,y,k] -------------
__global__ __launch_bounds__(256) void k_ifft_cols(const float* __restrict__ ocre,
                                                   const float* __restrict__ ocim,
                                                   float* __restrict__ r2re,
                                                   float* __restrict__ r2im) {
    __shared__ float2 xs[256], ys[256];
    int t = threadIdx.x;
    int bid = blockIdx.x;
    int k = bid % WF;
    int bc = bid / WF;
    size_t base = ((size_t)bc*WF + k)*HH;
    xs[t] = make_float2(ocre[base + t], ocim[base + t]);
    __syncthreads();
    float2 X = fft256_lds<1>(xs, ys, t);
    size_t ob = ((size_t)bc*HH + t)*WF + k;
    r2re[ob] = X.x * (1.0f/256.0f);
    r2im[ob] = X.y * (1.0f/256.0f);
}

// ------------- K7: hermitian row irfft + abs -> xr[b,c,y,x] -------------
__global__ __launch_bounds__(256) void k_irfft_rows(const float* __restrict__ r2re,
                                                    const float* __restrict__ r2im,
                                                    float* __restrict__ xr) {
    __shared__ float2 xs[256], ys[256];
    int t = threadIdx.x;
    int bid = blockIdx.x;
    int y = bid & 255;
    int bc = bid >> 8;
    size_t base = ((size_t)bc*HH + y)*WF;
    if (t < WF) xs[t] = make_float2(r2re[base + t], r2im[base + t]);
    __syncthreads();
    if (t >= WF) {                      // hermitian extension (imag of bins 0/128 kept; real part taken at end)
        float2 v = xs[256 - t];
        xs[t] = make_float2(v.x, -v.y);
    }
    __syncthreads();
    float2 X = fft256_lds<1>(xs, ys, t);
    xr[((size_t)bc*HH + y)*WW + t] = fabsf(X.x * (1.0f/256.0f));
}

// ------------- K8: final 5x5 conv, split in 2 channel-halves (grid 2048) -------------
// h==0: channels 0..31, acc starts at bias, writes pbuf. h==1: channels 32..63,
// acc starts at 0, writes out. k_add then merges.
__global__ __launch_bounds__(256) void k_conv5s(const float* __restrict__ xr,
                                                const float* __restrict__ w0,
                                                const float* __restrict__ b0,
                                                float* __restrict__ pbuf,
                                                float* __restrict__ out) {
    __shared__ float rl[5][260];
    int tid = threadIdx.x;                // x
    int bid = blockIdx.x;
    int h = bid >> 10;
    int y = bid & 255;
    int b = (bid >> 8) & 3;
    float acc[64];
    #pragma unroll
    for (int o = 0; o < 64; ++o) acc[o] = h ? 0.f : b0[o];
    for (int ci = 0; ci < 32; ++ci) {
        int c = h*32 + ci;
        __syncthreads();
        const float* xb = xr + (size_t)(b*CC + c)*HH*WW;
        #pragma unroll
        for (int dy = 0; dy < 5; ++dy) {
            int yy = y + dy - 2;
            const float* row = xb + (size_t)yy*WW;
            int x0 = tid - 2;
            rl[dy][tid] = (yy >= 0 && yy < HH && x0 >= 0) ? row[x0] : 0.f;
            if (tid < 4) {
                int x1 = 254 + tid;
                rl[dy][256 + tid] = (yy >= 0 && yy < HH && x1 < WW) ? row[x1] : 0.f;
            }
        }
        __syncthreads();
        float r[25];
        #pragma unroll
        for (int dy = 0; dy < 5; ++dy)
            #pragma unroll
            for (int dx = 0; dx < 5; ++dx)
                r[dy*5+dx] = rl[dy][tid + dx];
        const float* wb = w0 + (size_t)c*25;
        #pragma unroll
        for (int o = 0; o < 64; ++o) {
            const float* wo = wb + (size_t)o*CC*25;
            float a = acc[o];
            #pragma unroll
            for (int t2 = 0; t2 < 25; ++t2) a += wo[t2] * r[t2];
            acc[o] = a;
        }
    }
    float* dst = h ? out : pbuf;
    size_t ob = ((size_t)(b*CC)*HH + y)*WW + tid;
    #pragma unroll
    for (int o = 0; o < 64; ++o) dst[ob + (size_t)o*HH*WW] = acc[o];
}

__global__ __launch_bounds__(256) void k_add(float* __restrict__ out,
                                             const float* __restrict__ p) {
    size_t i = ((size_t)blockIdx.x*256 + threadIdx.x)*4;
    float4 a = *(float4*)(out + i);
    float4 q = *(const float4*)(p + i);
    a.x += q.x; a.y += q.y; a.z += q.z; a.w += q.w;
    *(float4*)(out + i) = a;
}

extern "C" void kernel_launch(void* const* d_in, const int* in_sizes, int n_in,
                              void* d_out, int out_size, void* d_ws, size_t ws_size,
                              hipStream_t stream) {
    const float* x    = (const float*)d_in[0];
    const float* wp_a = (const float*)d_in[1];
    const float* bp_a = (const float*)d_in[2];
    const float* wc_a = (const float*)d_in[3];
    const float* w1_a = (const float*)d_in[4];
    const float* b1_a = (const float*)d_in[5];
    const float* wp_p = (const float*)d_in[6];
    const float* bp_p = (const float*)d_in[7];
    const float* wc_p = (const float*)d_in[8];
    const float* w1_p = (const float*)d_in[9];
    const float* b1_p = (const float*)d_in[10];
    const float* w0   = (const float*)d_in[11];
    const float* b0   = (const float*)d_in[12];
    float* out = (float*)d_out;
    float* ws  = (float*)d_ws;

    // Workspace map (floats). Peak = 4*NS + off/wct = 154.6 MB (validated fits).
    //   R0 (2*NS): r1re/r1im -> ampc/phac -> r2re/r2im -> pbuf (conv5 partial)
    //   R1 (2*NS): amp/pha  -> A3/P3 -> ocre/ocim (in-place) -> xr
    //   R2: offa/offp + wcta/wctp
    float* R0 = ws;
    float* R1 = ws + 2*NS;
    float* R2 = ws + 4*NS;

    float* r1re = R0;
    float* r1im = R0 + NS;
    float* amp  = R1;
    float* pha  = R1 + NS;
    float* ampc = R0;
    float* phac = R0 + NS;
    size_t offsz = (size_t)BB*18*NPIX;       // 2,377,728
    float* offa = R2;
    float* offp = R2 + offsz;
    float* wcta = R2 + 2*offsz;
    float* wctp = wcta + 9*64*64;
    float* A3   = R1;
    float* P3   = R1 + NS;
    float* r2re = R0;
    float* r2im = R0 + NS;
    float* xrp  = R1;
    float* pbuf = R0;        // 16.78M floats <= 2*NS capacity

    k_wt<<<144, 256, 0, stream>>>(wc_a, wcta);
    k_wt<<<144, 256, 0, stream>>>(wc_p, wctp);
    k_fft_rows<<<BB*CC*HH, 256, 0, stream>>>(x, r1re, r1im);
    k_fft_cols<<<BB*CC*WF, 256, 0, stream>>>(r1re, r1im, amp, pha);
    k_pack<<<BB*WF*4, 256, 0, stream>>>(amp, ampc);
    k_pack<<<BB*WF*4, 256, 0, stream>>>(pha, phac);
    k_off_conv<<<BB*18*WF, 256, 0, stream>>>(amp, wp_a, bp_a, offa);
    k_off_conv<<<BB*18*WF, 256, 0, stream>>>(pha, wp_p, bp_p, offp);
    k_deform<<<BB*WF*16, 256, 0, stream>>>(ampc, offa, wcta, A3);
    k_deform<<<BB*WF*16, 256, 0, stream>>>(phac, offp, wctp, P3);
    k_combine<<<BB*WF*4, 256, 0, stream>>>(ampc, phac, A3, P3, w1_a, b1_a, w1_p, b1_p);
    k_ifft_cols<<<BB*CC*WF, 256, 0, stream>>>(A3, P3, r2re, r2im);
    k_irfft_rows<<<BB*CC*HH, 256, 0, stream>>>(r2re, r2im, xrp);
    k_conv5s<<<BB*HH*2, 256, 0, stream>>>(xrp, w0, b0, pbuf, out);
    k_add<<<(BB*CC*HH*WW)/1024, 256, 0, stream>>>(out, pbuf);
}

// Round 4
// 4132.669 us; speedup vs baseline: 1.5983x; 1.0443x over previous
//
#include <hip/hip_runtime.h>
#include <math.h>

#define BB 4
#define CC 64
#define HH 256
#define WW 256
#define WF 129
#define NPIX (WF*HH)                 // 33024
#define NS ((size_t)BB*CC*NPIX)      // 8454144 floats per plane-set
#define TWOPI 6.283185307179586f

// ---------------- four-step 256-point complex FFT in LDS ----------------
__device__ __forceinline__ float2 cmulf(float2 a, float2 b) {
    return make_float2(a.x*b.x - a.y*b.y, a.x*b.y + a.y*b.x);
}

// xs fully populated + __syncthreads() done by caller. SIGN=-1 fwd, +1 inv.
// Returns X[t] for thread t. Clobbers ys.
template<int SIGN>
__device__ __forceinline__ float2 fft256_lds(const float2* __restrict__ xs,
                                             float2* __restrict__ ys, int t) {
    int k1 = t & 15, n2 = t >> 4;
    float s1, c1;
    sincosf((float)SIGN * (TWOPI/16.f) * (float)k1, &s1, &c1);
    float2 rb = make_float2(c1, s1);
    float2 w = make_float2(1.f, 0.f);
    float2 acc = make_float2(0.f, 0.f);
    #pragma unroll
    for (int n1 = 0; n1 < 16; ++n1) {
        float2 v = xs[n1*16 + n2];
        acc.x = fmaf(v.x, w.x, fmaf(-v.y, w.y, acc.x));
        acc.y = fmaf(v.x, w.y, fmaf( v.y, w.x, acc.y));
        w = cmulf(w, rb);
    }
    float s2, c2;
    sincosf((float)SIGN * (TWOPI/256.f) * (float)(n2*k1), &s2, &c2);
    ys[t] = cmulf(acc, make_float2(c2, s2));
    __syncthreads();
    float s3, c3;
    sincosf((float)SIGN * (TWOPI/16.f) * (float)n2, &s3, &c3);
    float2 rb2 = make_float2(c3, s3);
    float2 w2 = make_float2(1.f, 0.f);
    float2 acc2 = make_float2(0.f, 0.f);
    #pragma unroll
    for (int m2 = 0; m2 < 16; ++m2) {
        float2 v = ys[m2*16 + k1];
        acc2.x = fmaf(v.x, w2.x, fmaf(-v.y, w2.y, acc2.x));
        acc2.y = fmaf(v.x, w2.y, fmaf( v.y, w2.x, acc2.y));
        w2 = cmulf(w2, rb2);
    }
    return acc2;
}

// ---------------- K1: row rfft (x[b,c,y,:] -> R1[b*C+c][k][y]) ----------------
__global__ __launch_bounds__(256) void k_fft_rows(const float* __restrict__ x,
                                                  float* __restrict__ r1re,
                                                  float* __restrict__ r1im) {
    __shared__ float2 xs[256], ys[256];
    int t = threadIdx.x;
    int bid = blockIdx.x;
    int y = bid & 255;
    int bc = bid >> 8;
    xs[t] = make_float2(x[(size_t)bc*HH*WW + (size_t)y*WW + t], 0.f);
    __syncthreads();
    float2 X = fft256_lds<-1>(xs, ys, t);
    if (t < WF) {
        r1re[((size_t)bc*WF + t)*HH + y] = X.x;
        r1im[((size_t)bc*WF + t)*HH + y] = X.y;
    }
}

// ------------- K2: column fft + amp/pha -------------
__global__ __launch_bounds__(256) void k_fft_cols(const float* __restrict__ r1re,
                                                  const float* __restrict__ r1im,
                                                  float* __restrict__ amp,
                                                  float* __restrict__ pha) {
    __shared__ float2 xs[256], ys[256];
    int t = threadIdx.x;
    int bid = blockIdx.x;
    int k = bid % WF;
    int bc = bid / WF;
    size_t base = ((size_t)bc*WF + k)*HH;
    xs[t] = make_float2(r1re[base + t], r1im[base + t]);
    __syncthreads();
    float2 X = fft256_lds<-1>(xs, ys, t);
    amp[base + t] = sqrtf(X.x*X.x + X.y*X.y);
    pha[base + t] = atan2f(X.y, X.x);
}

// ------------- K_pack: [b,c,k,m] -> channel-innermost [b,k,m,c] -------------
__global__ __launch_bounds__(256) void k_pack(const float* __restrict__ src,
                                              float* __restrict__ dst) {
    __shared__ float tile[64][65];
    int tid = threadIdx.x;
    int bid = blockIdx.x;
    int it = bid & 3;
    int rest = bid >> 2;
    int k = rest % WF;
    int b = rest / WF;
    int i0 = it*64;
    int ii = tid & 63;
    int cg = tid >> 6;
    for (int rep = 0; rep < 16; ++rep) {
        int c = cg*16 + rep;
        tile[c][ii] = src[(size_t)(b*CC + c)*NPIX + (size_t)k*HH + i0 + ii];
    }
    __syncthreads();
    for (int rep = 0; rep < 16; ++rep) {
        int m = cg*16 + rep;
        dst[((size_t)(b*WF + k)*HH + i0 + m)*CC + ii] = tile[ii][m];
    }
}

// ------------- K_wt: wc[oc][c][3][3] -> wct[pos][c][oc] -------------
__global__ void k_wt(const float* __restrict__ wc, float* __restrict__ wct) {
    int idx = blockIdx.x*256 + threadIdx.x;
    if (idx < 9*64*64) {
        int oc = idx & 63;
        int t = idx >> 6;
        int c = t & 63;
        int pos = t >> 6;
        wct[idx] = wc[((size_t)oc*64 + c)*9 + pos];
    }
}

// ------------- K3: offset conv 3x3 -------------
__global__ __launch_bounds__(256) void k_off_conv(const float* __restrict__ img,
                                                  const float* __restrict__ wp,
                                                  const float* __restrict__ bp,
                                                  float* __restrict__ off) {
    int tid = threadIdx.x;
    int bid = blockIdx.x;
    int j = bid % WF;
    int t = bid / WF;
    int oc = t % 18;
    int b = t / 18;
    float acc = bp[oc];
    for (int c = 0; c < CC; ++c) {
        const float* ib = img + (size_t)(b*CC + c)*NPIX;
        const float* wb = wp + ((size_t)oc*CC + c)*9;
        #pragma unroll
        for (int dj = 0; dj < 3; ++dj) {
            int jj = j + dj - 1;
            if (jj < 0 || jj >= WF) continue;
            const float* col = ib + (size_t)jj*HH;
            #pragma unroll
            for (int di = 0; di < 3; ++di) {
                int ii = tid + di - 1;
                float v = (ii >= 0 && ii < HH) ? col[ii] : 0.f;
                acc += wb[di*3 + dj] * v;
            }
        }
    }
    off[((size_t)(b*18 + oc)*WF + j)*HH + tid] = acc;
}

// ------------- K4: deformable sampling + stride-3 conv, fused -------------
__global__ __launch_bounds__(256) void k_deform(const float* __restrict__ imgc,
                                                const float* __restrict__ off,
                                                const float* __restrict__ wct,
                                                float* __restrict__ out) {
    __shared__ int   cidx[4][144];
    __shared__ float cwgt[4][144];
    __shared__ __align__(16) float S[16*580];
    int tid = threadIdx.x;
    int bid = blockIdx.x;
    int it = bid & 15;
    int rest = bid >> 4;
    int j = rest % WF;
    int b = rest / WF;
    int i0 = it * 16;

    if (tid < 144) {
        int pix = tid / 9;
        int pos = tid % 9;
        int ki = pos / 3, kj = pos % 3;
        int i = i0 + pix;
        int r = 3*i + ki - 1;
        int s = 3*j + kj - 1;
        float g[4] = {0.f,0.f,0.f,0.f};
        int ix[4] = {-1,-1,-1,-1};
        if (r >= 0 && s >= 0) {
            int hq = r/3, nx = r%3;
            int wq = s/3, ny = s%3;
            int n = nx*3 + ny;
            float ox = off[((size_t)(b*18 + n)*WF + wq)*HH + hq];
            float oy = off[((size_t)(b*18 + 9 + n)*WF + wq)*HH + hq];
            float pxf = (float)(hq + nx) + ox;
            float pyf = (float)(wq + ny) + oy;
            float qx = floorf(pxf), qy = floorf(pyf);
            float qltx = fminf(fmaxf(qx, 0.f), 257.f);
            float qlty = fminf(fmaxf(qy, 0.f), 130.f);
            float qrbx = fminf(fmaxf(qx + 1.f, 0.f), 257.f);
            float qrby = fminf(fmaxf(qy + 1.f, 0.f), 130.f);
            float pxc = fminf(fmaxf(pxf, 0.f), 257.f);
            float pyc = fminf(fmaxf(pyf, 0.f), 130.f);
            float glt = (1.f + (qltx - pxc)) * (1.f + (qlty - pyc));
            float grb = (1.f - (qrbx - pxc)) * (1.f - (qrby - pyc));
            float glb = (1.f + (qltx - pxc)) * (1.f - (qrby - pyc));
            float grt = (1.f - (qrbx - pxc)) * (1.f + (qlty - pyc));
            int ax0 = (int)qltx, ax1 = (int)qrbx;
            int ay0 = (int)qlty, ay1 = (int)qrby;
            int cx[4] = {ax0, ax1, ax0, ax1};
            int cy[4] = {ay0, ay1, ay1, ay0};
            g[0]=glt; g[1]=grb; g[2]=glb; g[3]=grt;
            #pragma unroll
            for (int q = 0; q < 4; ++q) {
                int a = cx[q], bq = cy[q];
                ix[q] = (a >= 1 && a <= 256 && bq >= 1 && bq <= 129)
                        ? ((bq-1)*HH + (a-1))*CC : -1;
            }
        }
        #pragma unroll
        for (int q = 0; q < 4; ++q) { cidx[q][tid] = ix[q]; cwgt[q][tid] = g[q]; }
    }
    __syncthreads();

    const float* cb = imgc + (size_t)b * (size_t)WF * HH * CC;
    for (int t = tid; t < 144*64; t += 256) {
        int combo = t >> 6;
        int c = t & 63;
        float sum = 0.f;
        #pragma unroll
        for (int q = 0; q < 4; ++q) {
            int ofs = cidx[q][combo];
            float v = (ofs >= 0) ? cb[(size_t)ofs + c] : 0.f;
            sum += cwgt[q][combo] * v;
        }
        int pix = combo / 9, pos = combo % 9;
        S[pix*580 + pos*64 + c] = sum;
    }
    __syncthreads();

    int pix = tid & 15;
    int oc0 = (tid >> 4) * 4;
    const float* Sp = &S[pix*580];
    float ac[4] = {0.f,0.f,0.f,0.f};
    for (int kk = 0; kk < 576; kk += 4) {
        float4 sv = *(const float4*)&Sp[kk];
        #pragma unroll
        for (int q = 0; q < 4; ++q) {
            float4 wv = *(const float4*)&wct[(size_t)(kk+q)*64 + oc0];
            float sc = (q==0)? sv.x : (q==1)? sv.y : (q==2)? sv.z : sv.w;
            ac[0] += sc*wv.x; ac[1] += sc*wv.y; ac[2] += sc*wv.z; ac[3] += sc*wv.w;
        }
    }
    size_t ob = (size_t)b*CC*NPIX + (size_t)j*HH + i0 + pix;
    #pragma unroll
    for (int q = 0; q < 4; ++q)
        out[ob + (size_t)(oc0+q)*NPIX] = ac[q];
}

// ------------- K5: fused 1x1 convs + trig combine -------------
__global__ __launch_bounds__(256) void k_combine(const float* __restrict__ ampc,
                                                 const float* __restrict__ phac,
                                                 float* __restrict__ a3,
                                                 float* __restrict__ p3,
                                                 const float* __restrict__ w1a,
                                                 const float* __restrict__ b1a,
                                                 const float* __restrict__ w1p,
                                                 const float* __restrict__ b1p) {
    __shared__ float la[64][65], lp[64][65];
    int tid = threadIdx.x;
    int bid = blockIdx.x;
    int quarter = bid & 3;
    int rest = bid >> 2;
    int j = rest % WF;
    int b = rest / WF;
    int i0 = quarter * 64;
    size_t gbase = ((size_t)(b*WF + j)*HH + i0) * CC;
    for (int rep = 0; rep < 16; ++rep) {
        int t = rep*256 + tid;
        int pix = t >> 6;
        int c = t & 63;
        la[c][pix] = ampc[gbase + t];
        lp[c][pix] = phac[gbase + t];
    }
    __syncthreads();
    int ii = tid & 63;
    int wv = tid >> 6;
    float acc_a[16], acc_p[16];
    #pragma unroll
    for (int q = 0; q < 16; ++q) { acc_a[q] = b1a[wv*16+q]; acc_p[q] = b1p[wv*16+q]; }
    for (int c = 0; c < CC; ++c) {
        float av = la[c][ii], pv = lp[c][ii];
        #pragma unroll
        for (int q = 0; q < 16; ++q) {
            acc_a[q] += w1a[(wv*16+q)*CC + c] * av;
            acc_p[q] += w1p[(wv*16+q)*CC + c] * pv;
        }
    }
    #pragma unroll
    for (int q = 0; q < 16; ++q) {
        int oc = wv*16 + q;
        size_t idx = (size_t)(b*CC + oc)*NPIX + (size_t)j*HH + i0 + ii;
        float a3v = a3[idx];
        float p3v = p3[idx];
        float s1, c1, s3, c3;
        sincosf(acc_p[q], &s1, &c1);
        sincosf(p3v, &s3, &c3);
        float re = acc_a[q]*c3 + a3v*c1 + 3e-8f;
        float im = a3v*s1 + acc_a[q]*s3 + 2e-8f;
        a3[idx] = re;
        p3[idx] = im;
    }
}

// ------------- K6: inverse column fft -------------
__global__ __launch_bounds__(256) void k_ifft_cols(const float* __restrict__ ocre,
                                                   const float* __restrict__ ocim,
                                                   float* __restrict__ r2re,
                                                   float* __restrict__ r2im) {
    __shared__ float2 xs[256], ys[256];
    int t = threadIdx.x;
    int bid = blockIdx.x;
    int k = bid % WF;
    int bc = bid / WF;
    size_t base = ((size_t)bc*WF + k)*HH;
    xs[t] = make_float2(ocre[base + t], ocim[base + t]);
    __syncthreads();
    float2 X = fft256_lds<1>(xs, ys, t);
    size_t ob = ((size_t)bc*HH + t)*WF + k;
    r2re[ob] = X.x * (1.0f/256.0f);
    r2im[ob] = X.y * (1.0f/256.0f);
}

// ------------- K7: hermitian row irfft + abs -------------
__global__ __launch_bounds__(256) void k_irfft_rows(const float* __restrict__ r2re,
                                                    const float* __restrict__ r2im,
                                                    float* __restrict__ xr) {
    __shared__ float2 xs[256], ys[256];
    int t = threadIdx.x;
    int bid = blockIdx.x;
    int y = bid & 255;
    int bc = bid >> 8;
    size_t base = ((size_t)bc*HH + y)*WF;
    if (t < WF) xs[t] = make_float2(r2re[base + t], r2im[base + t]);
    __syncthreads();
    if (t >= WF) {
        float2 v = xs[256 - t];
        xs[t] = make_float2(v.x, -v.y);
    }
    __syncthreads();
    float2 X = fft256_lds<1>(xs, ys, t);
    xr[((size_t)bc*HH + y)*WW + t] = fabsf(X.x * (1.0f/256.0f));
}

// ------------- K8: final 5x5 conv, oc-group tiled (16 acc/thread) -------------
// grid = BB*HH*4: y = bid&255, b = (bid>>8)&3, g = bid>>10 (oc group of 16).
__global__ __launch_bounds__(256) void k_conv5g(const float* __restrict__ xr,
                                                const float* __restrict__ w0,
                                                const float* __restrict__ b0,
                                                float* __restrict__ out) {
    __shared__ float rl[5][260];
    int tid = threadIdx.x;                // x
    int bid = blockIdx.x;
    int y = bid & 255;
    int b = (bid >> 8) & 3;
    int g = bid >> 10;                    // 0..3
    float acc[16];
    #pragma unroll
    for (int o = 0; o < 16; ++o) acc[o] = b0[g*16 + o];
    for (int c = 0; c < CC; ++c) {
        __syncthreads();
        const float* xb = xr + (size_t)(b*CC + c)*HH*WW;
        #pragma unroll
        for (int dy = 0; dy < 5; ++dy) {
            int yy = y + dy - 2;
            const float* row = xb + (size_t)yy*WW;
            int x0 = tid - 2;
            rl[dy][tid] = (yy >= 0 && yy < HH && x0 >= 0) ? row[x0] : 0.f;
            if (tid < 4) {
                int x1 = 254 + tid;
                rl[dy][256 + tid] = (yy >= 0 && yy < HH && x1 < WW) ? row[x1] : 0.f;
            }
        }
        __syncthreads();
        float r[25];
        #pragma unroll
        for (int dy = 0; dy < 5; ++dy)
            #pragma unroll
            for (int dx = 0; dx < 5; ++dx)
                r[dy*5+dx] = rl[dy][tid + dx];
        const float* wb = w0 + ((size_t)(g*16)*CC + c)*25;
        #pragma unroll
        for (int o = 0; o < 16; ++o) {
            const float* wo = wb + (size_t)o*CC*25;
            float a = acc[o];
            #pragma unroll
            for (int t2 = 0; t2 < 25; ++t2) a += wo[t2] * r[t2];
            acc[o] = a;
        }
    }
    size_t ob = ((size_t)(b*CC + g*16)*HH + y)*WW + tid;
    #pragma unroll
    for (int o = 0; o < 16; ++o) out[ob + (size_t)o*HH*WW] = acc[o];
}

extern "C" void kernel_launch(void* const* d_in, const int* in_sizes, int n_in,
                              void* d_out, int out_size, void* d_ws, size_t ws_size,
                              hipStream_t stream) {
    const float* x    = (const float*)d_in[0];
    const float* wp_a = (const float*)d_in[1];
    const float* bp_a = (const float*)d_in[2];
    const float* wc_a = (const float*)d_in[3];
    const float* w1_a = (const float*)d_in[4];
    const float* b1_a = (const float*)d_in[5];
    const float* wp_p = (const float*)d_in[6];
    const float* bp_p = (const float*)d_in[7];
    const float* wc_p = (const float*)d_in[8];
    const float* w1_p = (const float*)d_in[9];
    const float* b1_p = (const float*)d_in[10];
    const float* w0   = (const float*)d_in[11];
    const float* b0   = (const float*)d_in[12];
    float* out = (float*)d_out;
    float* ws  = (float*)d_ws;

    // Workspace map (floats). Peak = 4*NS + off/wct = 154.6 MB.
    float* R0 = ws;
    float* R1 = ws + 2*NS;
    float* R2 = ws + 4*NS;

    float* r1re = R0;
    float* r1im = R0 + NS;
    float* amp  = R1;
    float* pha  = R1 + NS;
    float* ampc = R0;
    float* phac = R0 + NS;
    size_t offsz = (size_t)BB*18*NPIX;
    float* offa = R2;
    float* offp = R2 + offsz;
    float* wcta = R2 + 2*offsz;
    float* wctp = wcta + 9*64*64;
    float* A3   = R1;
    float* P3   = R1 + NS;
    float* r2re = R0;
    float* r2im = R0 + NS;
    float* xrp  = R1;

    k_wt<<<144, 256, 0, stream>>>(wc_a, wcta);
    k_wt<<<144, 256, 0, stream>>>(wc_p, wctp);
    k_fft_rows<<<BB*CC*HH, 256, 0, stream>>>(x, r1re, r1im);
    k_fft_cols<<<BB*CC*WF, 256, 0, stream>>>(r1re, r1im, amp, pha);
    k_pack<<<BB*WF*4, 256, 0, stream>>>(amp, ampc);
    k_pack<<<BB*WF*4, 256, 0, stream>>>(pha, phac);
    k_off_conv<<<BB*18*WF, 256, 0, stream>>>(amp, wp_a, bp_a, offa);
    k_off_conv<<<BB*18*WF, 256, 0, stream>>>(pha, wp_p, bp_p, offp);
    k_deform<<<BB*WF*16, 256, 0, stream>>>(ampc, offa, wcta, A3);
    k_deform<<<BB*WF*16, 256, 0, stream>>>(phac, offp, wctp, P3);
    k_combine<<<BB*WF*4, 256, 0, stream>>>(ampc, phac, A3, P3, w1_a, b1_a, w1_p, b1_p);
    k_ifft_cols<<<BB*CC*WF, 256, 0, stream>>>(A3, P3, r2re, r2im);
    k_irfft_rows<<<BB*CC*HH, 256, 0, stream>>>(r2re, r2im, xrp);
    k_conv5g<<<BB*HH*4, 256, 0, stream>>>(xrp, w0, b0, out);
}

// Round 5
// 3539.894 us; speedup vs baseline: 1.8659x; 1.1675x over previous
//
#include <hip/hip_runtime.h>
#include <math.h>

#define BB 4
#define CC 64
#define HH 256
#define WW 256
#define WF 129
#define NPIX (WF*HH)                 // 33024
#define NS ((size_t)BB*CC*NPIX)      // 8454144 floats per plane-set
#define TWOPI 6.283185307179586f

// ---------------- four-step 256-point complex FFT in LDS ----------------
__device__ __forceinline__ float2 cmulf(float2 a, float2 b) {
    return make_float2(a.x*b.x - a.y*b.y, a.x*b.y + a.y*b.x);
}

template<int SIGN>
__device__ __forceinline__ float2 fft256_lds(const float2* __restrict__ xs,
                                             float2* __restrict__ ys, int t) {
    int k1 = t & 15, n2 = t >> 4;
    float s1, c1;
    sincosf((float)SIGN * (TWOPI/16.f) * (float)k1, &s1, &c1);
    float2 rb = make_float2(c1, s1);
    float2 w = make_float2(1.f, 0.f);
    float2 acc = make_float2(0.f, 0.f);
    #pragma unroll
    for (int n1 = 0; n1 < 16; ++n1) {
        float2 v = xs[n1*16 + n2];
        acc.x = fmaf(v.x, w.x, fmaf(-v.y, w.y, acc.x));
        acc.y = fmaf(v.x, w.y, fmaf( v.y, w.x, acc.y));
        w = cmulf(w, rb);
    }
    float s2, c2;
    sincosf((float)SIGN * (TWOPI/256.f) * (float)(n2*k1), &s2, &c2);
    ys[t] = cmulf(acc, make_float2(c2, s2));
    __syncthreads();
    float s3, c3;
    sincosf((float)SIGN * (TWOPI/16.f) * (float)n2, &s3, &c3);
    float2 rb2 = make_float2(c3, s3);
    float2 w2 = make_float2(1.f, 0.f);
    float2 acc2 = make_float2(0.f, 0.f);
    #pragma unroll
    for (int m2 = 0; m2 < 16; ++m2) {
        float2 v = ys[m2*16 + k1];
        acc2.x = fmaf(v.x, w2.x, fmaf(-v.y, w2.y, acc2.x));
        acc2.y = fmaf(v.x, w2.y, fmaf( v.y, w2.x, acc2.y));
        w2 = cmulf(w2, rb2);
    }
    return acc2;
}

// ---------------- K1: row rfft (x[b,c,y,:] -> R1[b*C+c][k][y]) ----------------
__global__ __launch_bounds__(256) void k_fft_rows(const float* __restrict__ x,
                                                  float* __restrict__ r1re,
                                                  float* __restrict__ r1im) {
    __shared__ float2 xs[256], ys[256];
    int t = threadIdx.x;
    int bid = blockIdx.x;
    int y = bid & 255;
    int bc = bid >> 8;
    xs[t] = make_float2(x[(size_t)bc*HH*WW + (size_t)y*WW + t], 0.f);
    __syncthreads();
    float2 X = fft256_lds<-1>(xs, ys, t);
    if (t < WF) {
        r1re[((size_t)bc*WF + t)*HH + y] = X.x;
        r1im[((size_t)bc*WF + t)*HH + y] = X.y;
    }
}

// ------------- K2: column fft + amp/pha -------------
__global__ __launch_bounds__(256) void k_fft_cols(const float* __restrict__ r1re,
                                                  const float* __restrict__ r1im,
                                                  float* __restrict__ amp,
                                                  float* __restrict__ pha) {
    __shared__ float2 xs[256], ys[256];
    int t = threadIdx.x;
    int bid = blockIdx.x;
    int k = bid % WF;
    int bc = bid / WF;
    size_t base = ((size_t)bc*WF + k)*HH;
    xs[t] = make_float2(r1re[base + t], r1im[base + t]);
    __syncthreads();
    float2 X = fft256_lds<-1>(xs, ys, t);
    amp[base + t] = sqrtf(X.x*X.x + X.y*X.y);
    pha[base + t] = atan2f(X.y, X.x);
}

// ------------- K_pack: [b,c,k,m] -> channel-innermost [b,k,m,c] -------------
__global__ __launch_bounds__(256) void k_pack(const float* __restrict__ src,
                                              float* __restrict__ dst) {
    __shared__ float tile[64][65];
    int tid = threadIdx.x;
    int bid = blockIdx.x;
    int it = bid & 3;
    int rest = bid >> 2;
    int k = rest % WF;
    int b = rest / WF;
    int i0 = it*64;
    int ii = tid & 63;
    int cg = tid >> 6;
    for (int rep = 0; rep < 16; ++rep) {
        int c = cg*16 + rep;
        tile[c][ii] = src[(size_t)(b*CC + c)*NPIX + (size_t)k*HH + i0 + ii];
    }
    __syncthreads();
    for (int rep = 0; rep < 16; ++rep) {
        int m = cg*16 + rep;
        dst[((size_t)(b*WF + k)*HH + i0 + m)*CC + ii] = tile[ii][m];
    }
}

// ------------- K_wt: wc[oc][c][3][3] -> wct[pos][c][oc] -------------
__global__ void k_wt(const float* __restrict__ wc, float* __restrict__ wct) {
    int idx = blockIdx.x*256 + threadIdx.x;
    if (idx < 9*64*64) {
        int oc = idx & 63;
        int t = idx >> 6;
        int c = t & 63;
        int pos = t >> 6;
        wct[idx] = wc[((size_t)oc*64 + c)*9 + pos];
    }
}

// ------------- K_w0t: w0[oc][c][5][5] -> w0t[c][tap][oc] -------------
__global__ void k_w0t(const float* __restrict__ w0, float* __restrict__ w0t) {
    int idx = blockIdx.x*256 + threadIdx.x;   // 64*25*64 = 102400
    if (idx < 64*25*64) {
        int oc = idx & 63;
        int t = idx >> 6;
        int tap = t % 25;
        int c = t / 25;
        w0t[idx] = w0[((size_t)oc*CC + c)*25 + tap];
    }
}

// ------------- K3: offset conv 3x3 -------------
__global__ __launch_bounds__(256) void k_off_conv(const float* __restrict__ img,
                                                  const float* __restrict__ wp,
                                                  const float* __restrict__ bp,
                                                  float* __restrict__ off) {
    int tid = threadIdx.x;
    int bid = blockIdx.x;
    int j = bid % WF;
    int t = bid / WF;
    int oc = t % 18;
    int b = t / 18;
    float acc = bp[oc];
    for (int c = 0; c < CC; ++c) {
        const float* ib = img + (size_t)(b*CC + c)*NPIX;
        const float* wb = wp + ((size_t)oc*CC + c)*9;
        #pragma unroll
        for (int dj = 0; dj < 3; ++dj) {
            int jj = j + dj - 1;
            if (jj < 0 || jj >= WF) continue;
            const float* col = ib + (size_t)jj*HH;
            #pragma unroll
            for (int di = 0; di < 3; ++di) {
                int ii = tid + di - 1;
                float v = (ii >= 0 && ii < HH) ? col[ii] : 0.f;
                acc += wb[di*3 + dj] * v;
            }
        }
    }
    off[((size_t)(b*18 + oc)*WF + j)*HH + tid] = acc;
}

// ------------- K4: deformable sampling + stride-3 conv, fused -------------
__global__ __launch_bounds__(256) void k_deform(const float* __restrict__ imgc,
                                                const float* __restrict__ off,
                                                const float* __restrict__ wct,
                                                float* __restrict__ out) {
    __shared__ int   cidx[4][144];
    __shared__ float cwgt[4][144];
    __shared__ __align__(16) float S[16*580];
    int tid = threadIdx.x;
    int bid = blockIdx.x;
    int it = bid & 15;
    int rest = bid >> 4;
    int j = rest % WF;
    int b = rest / WF;
    int i0 = it * 16;

    if (tid < 144) {
        int pix = tid / 9;
        int pos = tid % 9;
        int ki = pos / 3, kj = pos % 3;
        int i = i0 + pix;
        int r = 3*i + ki - 1;
        int s = 3*j + kj - 1;
        float g[4] = {0.f,0.f,0.f,0.f};
        int ix[4] = {-1,-1,-1,-1};
        if (r >= 0 && s >= 0) {
            int hq = r/3, nx = r%3;
            int wq = s/3, ny = s%3;
            int n = nx*3 + ny;
            float ox = off[((size_t)(b*18 + n)*WF + wq)*HH + hq];
            float oy = off[((size_t)(b*18 + 9 + n)*WF + wq)*HH + hq];
            float pxf = (float)(hq + nx) + ox;
            float pyf = (float)(wq + ny) + oy;
            float qx = floorf(pxf), qy = floorf(pyf);
            float qltx = fminf(fmaxf(qx, 0.f), 257.f);
            float qlty = fminf(fmaxf(qy, 0.f), 130.f);
            float qrbx = fminf(fmaxf(qx + 1.f, 0.f), 257.f);
            float qrby = fminf(fmaxf(qy + 1.f, 0.f), 130.f);
            float pxc = fminf(fmaxf(pxf, 0.f), 257.f);
            float pyc = fminf(fmaxf(pyf, 0.f), 130.f);
            float glt = (1.f + (qltx - pxc)) * (1.f + (qlty - pyc));
            float grb = (1.f - (qrbx - pxc)) * (1.f - (qrby - pyc));
            float glb = (1.f + (qltx - pxc)) * (1.f - (qrby - pyc));
            float grt = (1.f - (qrbx - pxc)) * (1.f + (qlty - pyc));
            int ax0 = (int)qltx, ax1 = (int)qrbx;
            int ay0 = (int)qlty, ay1 = (int)qrby;
            int cx[4] = {ax0, ax1, ax0, ax1};
            int cy[4] = {ay0, ay1, ay1, ay0};
            g[0]=glt; g[1]=grb; g[2]=glb; g[3]=grt;
            #pragma unroll
            for (int q = 0; q < 4; ++q) {
                int a = cx[q], bq = cy[q];
                ix[q] = (a >= 1 && a <= 256 && bq >= 1 && bq <= 129)
                        ? ((bq-1)*HH + (a-1))*CC : -1;
            }
        }
        #pragma unroll
        for (int q = 0; q < 4; ++q) { cidx[q][tid] = ix[q]; cwgt[q][tid] = g[q]; }
    }
    __syncthreads();

    const float* cb = imgc + (size_t)b * (size_t)WF * HH * CC;
    for (int t = tid; t < 144*64; t += 256) {
        int combo = t >> 6;
        int c = t & 63;
        float sum = 0.f;
        #pragma unroll
        for (int q = 0; q < 4; ++q) {
            int ofs = cidx[q][combo];
            float v = (ofs >= 0) ? cb[(size_t)ofs + c] : 0.f;
            sum += cwgt[q][combo] * v;
        }
        int pix = combo / 9, pos = combo % 9;
        S[pix*580 + pos*64 + c] = sum;
    }
    __syncthreads();

    int pix = tid & 15;
    int oc0 = (tid >> 4) * 4;
    const float* Sp = &S[pix*580];
    float ac[4] = {0.f,0.f,0.f,0.f};
    for (int kk = 0; kk < 576; kk += 4) {
        float4 sv = *(const float4*)&Sp[kk];
        #pragma unroll
        for (int q = 0; q < 4; ++q) {
            float4 wv = *(const float4*)&wct[(size_t)(kk+q)*64 + oc0];
            float sc = (q==0)? sv.x : (q==1)? sv.y : (q==2)? sv.z : sv.w;
            ac[0] += sc*wv.x; ac[1] += sc*wv.y; ac[2] += sc*wv.z; ac[3] += sc*wv.w;
        }
    }
    size_t ob = (size_t)b*CC*NPIX + (size_t)j*HH + i0 + pix;
    #pragma unroll
    for (int q = 0; q < 4; ++q)
        out[ob + (size_t)(oc0+q)*NPIX] = ac[q];
}

// ------------- K5: fused 1x1 convs + trig combine -------------
__global__ __launch_bounds__(256) void k_combine(const float* __restrict__ ampc,
                                                 const float* __restrict__ phac,
                                                 float* __restrict__ a3,
                                                 float* __restrict__ p3,
                                                 const float* __restrict__ w1a,
                                                 const float* __restrict__ b1a,
                                                 const float* __restrict__ w1p,
                                                 const float* __restrict__ b1p) {
    __shared__ float la[64][65], lp[64][65];
    int tid = threadIdx.x;
    int bid = blockIdx.x;
    int quarter = bid & 3;
    int rest = bid >> 2;
    int j = rest % WF;
    int b = rest / WF;
    int i0 = quarter * 64;
    size_t gbase = ((size_t)(b*WF + j)*HH + i0) * CC;
    for (int rep = 0; rep < 16; ++rep) {
        int t = rep*256 + tid;
        int pix = t >> 6;
        int c = t & 63;
        la[c][pix] = ampc[gbase + t];
        lp[c][pix] = phac[gbase + t];
    }
    __syncthreads();
    int ii = tid & 63;
    int wv = tid >> 6;
    float acc_a[16], acc_p[16];
    #pragma unroll
    for (int q = 0; q < 16; ++q) { acc_a[q] = b1a[wv*16+q]; acc_p[q] = b1p[wv*16+q]; }
    for (int c = 0; c < CC; ++c) {
        float av = la[c][ii], pv = lp[c][ii];
        #pragma unroll
        for (int q = 0; q < 16; ++q) {
            acc_a[q] += w1a[(wv*16+q)*CC + c] * av;
            acc_p[q] += w1p[(wv*16+q)*CC + c] * pv;
        }
    }
    #pragma unroll
    for (int q = 0; q < 16; ++q) {
        int oc = wv*16 + q;
        size_t idx = (size_t)(b*CC + oc)*NPIX + (size_t)j*HH + i0 + ii;
        float a3v = a3[idx];
        float p3v = p3[idx];
        float s1, c1, s3, c3;
        sincosf(acc_p[q], &s1, &c1);
        sincosf(p3v, &s3, &c3);
        float re = acc_a[q]*c3 + a3v*c1 + 3e-8f;
        float im = a3v*s1 + acc_a[q]*s3 + 2e-8f;
        a3[idx] = re;
        p3[idx] = im;
    }
}

// ------------- K6: inverse column fft -------------
__global__ __launch_bounds__(256) void k_ifft_cols(const float* __restrict__ ocre,
                                                   const float* __restrict__ ocim,
                                                   float* __restrict__ r2re,
                                                   float* __restrict__ r2im) {
    __shared__ float2 xs[256], ys[256];
    int t = threadIdx.x;
    int bid = blockIdx.x;
    int k = bid % WF;
    int bc = bid / WF;
    size_t base = ((size_t)bc*WF + k)*HH;
    xs[t] = make_float2(ocre[base + t], ocim[base + t]);
    __syncthreads();
    float2 X = fft256_lds<1>(xs, ys, t);
    size_t ob = ((size_t)bc*HH + t)*WF + k;
    r2re[ob] = X.x * (1.0f/256.0f);
    r2im[ob] = X.y * (1.0f/256.0f);
}

// ------------- K7: hermitian row irfft + abs -------------
__global__ __launch_bounds__(256) void k_irfft_rows(const float* __restrict__ r2re,
                                                    const float* __restrict__ r2im,
                                                    float* __restrict__ xr) {
    __shared__ float2 xs[256], ys[256];
    int t = threadIdx.x;
    int bid = blockIdx.x;
    int y = bid & 255;
    int bc = bid >> 8;
    size_t base = ((size_t)bc*HH + y)*WF;
    if (t < WF) xs[t] = make_float2(r2re[base + t], r2im[base + t]);
    __syncthreads();
    if (t >= WF) {
        float2 v = xs[256 - t];
        xs[t] = make_float2(v.x, -v.y);
    }
    __syncthreads();
    float2 X = fft256_lds<1>(xs, ys, t);
    xr[((size_t)bc*HH + y)*WW + t] = fabsf(X.x * (1.0f/256.0f));
}

// ------------- K8: final 5x5 conv, lane = oc, vector weights -------------
// grid = BB*HH*4: q = bid&3 (x-quarter), y = (bid>>2)&255, b = bid>>10.
// lane (tid&63) = oc; wave (tid>>6) covers 16 pixels. Weights from w0t[c][tap][oc]
// (per-lane coalesced); pixels broadcast from LDS. Epilogue transposes via LDS
// so global stores are coalesced along x.
__global__ __launch_bounds__(256) void k_conv5v(const float* __restrict__ xr,
                                                const float* __restrict__ w0t,
                                                const float* __restrict__ b0,
                                                float* __restrict__ out) {
    __shared__ __align__(16) float xs[5][72];
    __shared__ float S[64][65];
    int tid = threadIdx.x;
    int bid = blockIdx.x;
    int q = bid & 3;
    int y = (bid >> 2) & 255;
    int b = bid >> 10;
    int lane = tid & 63;       // oc
    int wv = tid >> 6;         // pixel sub-group, 16 px each
    int x0 = q * 64;
    float bias = b0[lane];
    float acc[16];
    #pragma unroll
    for (int p = 0; p < 16; ++p) acc[p] = bias;

    for (int c = 0; c < CC; ++c) {
        __syncthreads();
        const float* xb = xr + (size_t)(b*CC + c)*HH*WW;
        for (int t = tid; t < 340; t += 256) {
            int dy = t / 68;
            int u = t - dy*68;
            int yy = y + dy - 2;
            int xx = x0 + u - 2;
            xs[dy][u] = (yy >= 0 && yy < HH && xx >= 0 && xx < WW)
                        ? xb[(size_t)yy*WW + xx] : 0.f;
        }
        float wreg[25];
        const float* wb = w0t + (size_t)c*25*64 + lane;
        #pragma unroll
        for (int j = 0; j < 25; ++j) wreg[j] = wb[j*64];
        __syncthreads();
        #pragma unroll
        for (int dy = 0; dy < 5; ++dy) {
            float rv[20];
            const float4* xp = (const float4*)&xs[dy][wv*16];
            #pragma unroll
            for (int v = 0; v < 5; ++v) {
                float4 f = xp[v];
                rv[v*4+0]=f.x; rv[v*4+1]=f.y; rv[v*4+2]=f.z; rv[v*4+3]=f.w;
            }
            #pragma unroll
            for (int dx = 0; dx < 5; ++dx) {
                float w = wreg[dy*5+dx];
                #pragma unroll
                for (int p = 0; p < 16; ++p)
                    acc[p] = fmaf(w, rv[p+dx], acc[p]);
            }
        }
    }
    __syncthreads();
    #pragma unroll
    for (int p = 0; p < 16; ++p) S[lane][wv*16 + p] = acc[p];
    __syncthreads();
    int px = tid & 63;
    #pragma unroll
    for (int rep = 0; rep < 16; ++rep) {
        int oc = wv*16 + rep;
        out[((size_t)(b*CC + oc)*HH + y)*WW + x0 + px] = S[oc][px];
    }
}

extern "C" void kernel_launch(void* const* d_in, const int* in_sizes, int n_in,
                              void* d_out, int out_size, void* d_ws, size_t ws_size,
                              hipStream_t stream) {
    const float* x    = (const float*)d_in[0];
    const float* wp_a = (const float*)d_in[1];
    const float* bp_a = (const float*)d_in[2];
    const float* wc_a = (const float*)d_in[3];
    const float* w1_a = (const float*)d_in[4];
    const float* b1_a = (const float*)d_in[5];
    const float* wp_p = (const float*)d_in[6];
    const float* bp_p = (const float*)d_in[7];
    const float* wc_p = (const float*)d_in[8];
    const float* w1_p = (const float*)d_in[9];
    const float* b1_p = (const float*)d_in[10];
    const float* w0   = (const float*)d_in[11];
    const float* b0   = (const float*)d_in[12];
    float* out = (float*)d_out;
    float* ws  = (float*)d_ws;

    // Workspace map (floats). Peak = 4*NS + off/wct/w0t ≈ 155 MB.
    float* R0 = ws;
    float* R1 = ws + 2*NS;
    float* R2 = ws + 4*NS;

    float* r1re = R0;
    float* r1im = R0 + NS;
    float* amp  = R1;
    float* pha  = R1 + NS;
    float* ampc = R0;
    float* phac = R0 + NS;
    size_t offsz = (size_t)BB*18*NPIX;
    float* offa = R2;
    float* offp = R2 + offsz;
    float* wcta = R2 + 2*offsz;
    float* wctp = wcta + 9*64*64;
    float* w0tp = wctp + 9*64*64;      // 64*25*64 = 102400 floats
    float* A3   = R1;
    float* P3   = R1 + NS;
    float* r2re = R0;
    float* r2im = R0 + NS;
    float* xrp  = R1;

    k_wt<<<144, 256, 0, stream>>>(wc_a, wcta);
    k_wt<<<144, 256, 0, stream>>>(wc_p, wctp);
    k_w0t<<<400, 256, 0, stream>>>(w0, w0tp);
    k_fft_rows<<<BB*CC*HH, 256, 0, stream>>>(x, r1re, r1im);
    k_fft_cols<<<BB*CC*WF, 256, 0, stream>>>(r1re, r1im, amp, pha);
    k_pack<<<BB*WF*4, 256, 0, stream>>>(amp, ampc);
    k_pack<<<BB*WF*4, 256, 0, stream>>>(pha, phac);
    k_off_conv<<<BB*18*WF, 256, 0, stream>>>(amp, wp_a, bp_a, offa);
    k_off_conv<<<BB*18*WF, 256, 0, stream>>>(pha, wp_p, bp_p, offp);
    k_deform<<<BB*WF*16, 256, 0, stream>>>(ampc, offa, wcta, A3);
    k_deform<<<BB*WF*16, 256, 0, stream>>>(phac, offp, wctp, P3);
    k_combine<<<BB*WF*4, 256, 0, stream>>>(ampc, phac, A3, P3, w1_a, b1_a, w1_p, b1_p);
    k_ifft_cols<<<BB*CC*WF, 256, 0, stream>>>(A3, P3, r2re, r2im);
    k_irfft_rows<<<BB*CC*HH, 256, 0, stream>>>(r2re, r2im, xrp);
    k_conv5v<<<BB*HH*4, 256, 0, stream>>>(xrp, w0tp, b0, out);
}